// Round 7
// baseline (30011.743 us; speedup 1.0000x reference)
//
#include <hip/hip_runtime.h>
#include <hip/hip_fp16.h>
#include <math.h>

// LSTM_11089605558768: T=16384 sequential steps, H=512, IN=32, OUT=1.
// Persistent scan, 32 worker wgs x 256 threads; each wg owns 16 h-elements
// (64 gate rows x 544 k, [W_hh | W_ih] folded).
//
// R13 = R12 (harness-proven shell: VGPR=144 pin HELD, WRITE=32768 no spill,
// 0 conflicts) + the missing s_sleep stagger. R12 post-mortem: without the
// sleep, the ping-pong probes issue in back-to-back pairs (A@0,B@eps,A'@L,
// B'@L+eps) -> samples land in near-simultaneous duplicated pairs -> the
// effective sampling period stayed L (not L/2), probe traffic doubled
// (FETCH 177->213MB) with zero info gain -> +4.6%. The theory was never
// tested. Fix: issue A, s_sleep(5) (~320cy ~= L/2), issue B. Phase is then
// self-preserving (each probe's reissue is tied to its own retirement):
// samples at L/2, L/2+320, 3L/2, 3L/2+320, ... = uniform period ~L/2.
// Barrier B waits on the MAX over ~124 pollers; max quantization drops
// ~L -> ~L/2 ~= 300cy of the ~1825cy step.
//  - Bounded ping-pong (2048 iters) + R6-proven blind fallback: hang-proof.
//  - Parity rule: tags at parity-q locations are == q (mod 2) -> a stale
//    dangler can never false-validate the next step. Danglers retire
//    oldest-first before any checked probe; one vmcnt(0) after the t-loop.
//  - x_t staged by wave 2 (idle during poll): pollers' vmcnt stream pure.
//  - Loop body otherwise BYTE-IDENTICAL to R6/R12 (R7-R10: any reshape makes
//    hipcc demote wreg[] to scratch; VGPR 96/88/64/52, WRITE 2x, +800cy/step).

#define T_STEPS 16384
#define IN_DIM  32
#define H_DIM   512
#define SLOTS   32
#define H_SLICE 16      // H_DIM / SLOTS
#define KTOT    544     // H_DIM + IN_DIM
#define CHUNK   136     // KTOT / 4 waves

typedef unsigned int uint32x4 __attribute__((ext_vector_type(4)));

__device__ __forceinline__ float fast_sigmoid(float v) {
  return 1.0f / (1.0f + __expf(-v));
}
__device__ __forceinline__ float fast_tanh(float v) {
  return 2.0f / (1.0f + __expf(-2.0f * v)) - 1.0f;  // 2*sigmoid(2x)-1
}

// --- packet I/O (always LLC-coherent: sc0 sc1) -----------------------------
__device__ __forceinline__ void store_pkt(unsigned int* p, unsigned int v) {
  asm volatile("global_store_dword %0, %1, off sc0 sc1"
               :: "v"(p), "v"(v) : "memory");
}
__device__ __forceinline__ uint32x4 load_pkt4(const unsigned int* p) {
  uint32x4 r;
  asm volatile("global_load_dwordx4 %0, %1, off sc0 sc1\n\ts_waitcnt vmcnt(0)"
               : "=&v"(r) : "v"(p) : "memory");
  return r;
}
__device__ __forceinline__ float pkt_to_f(unsigned int v) {
  return __half2float(__ushort_as_half((unsigned short)(v & 0xFFFFu)));
}
__device__ __forceinline__ bool tag_ok(const uint32x4& r, unsigned int tg) {
  return (r.x >> 16) == tg && (r.y >> 16) == tg &&
         (r.z >> 16) == tg && (r.w >> 16) == tg;
}
__device__ __forceinline__ void stage4(float* dst, const uint32x4& r) {
  float4 hv4;
  hv4.x = pkt_to_f(r.x);
  hv4.y = pkt_to_f(r.y);
  hv4.z = pkt_to_f(r.z);
  hv4.w = pkt_to_f(r.w);
  *(float4*)dst = hv4;  // contiguous float4: 0 bank conflicts (R6-proven)
}

__launch_bounds__(256, 1)
__global__ void lstm_scan_kernel(
    const float* __restrict__ x,     // [T, 32]
    const float* __restrict__ Wih,   // [2048, 32]
    const float* __restrict__ Whh,   // [2048, 512]
    const float* __restrict__ bih,   // [2048]
    const float* __restrict__ bhh,   // [2048]
    const float* __restrict__ Wlin,  // [512]
    const float* __restrict__ blin,  // [1]
    float* __restrict__ out,         // [1]
    unsigned int* pub)               // [2][512] 4B packets (d_ws)
{
  const int slot = blockIdx.x;       // 0..31
  const int tid  = threadIdx.x;
  const int w    = tid >> 6;   // wave 0..3 -> k-chunk
  const int l    = tid & 63;   // lane -> local gate row

  __shared__ __align__(16) float hshm[KTOT];  // [0,512)=h(t), [512,544)=x_t
  __shared__ float red[256];                  // per-wave partials

  // local row l: 0..15 = i, 16..31 = f, 32..47 = g, 48..63 = o
  const int R = (l >> 4) * H_DIM + slot * H_SLICE + (l & 15);

  // Persistent weight slice -> registers, then PIN with opaque asm identity
  // so the compiler cannot rematerialize the loads inside the t-loop.
  float wreg[CHUNK];
  #pragma unroll
  for (int j = 0; j < CHUNK; ++j) {
    const int k = w * CHUNK + j;
    wreg[j] = (k < H_DIM) ? Whh[R * H_DIM + k]
                          : Wih[R * IN_DIM + (k - H_DIM)];
  }
  #pragma unroll
  for (int j = 0; j < CHUNK; ++j)
    asm volatile("v_mov_b32 %0, %0" : "+v"(wreg[j]));

  const float bias = (w == 0) ? (bih[R] + bhh[R]) : 0.0f;

  float c = 0.0f;  // cell state: wave 0, lanes 0..15 (h index slot*16 + l)

  // Polling assignment (R6-proven): tid<128 polls packets [4*tid, 4*tid+4);
  // own-slot group skipped (wave-0 epilogue provides it in fp32).
  const bool poller = (tid < 128) && ((tid >> 2) != slot);
  const bool xthr   = (tid >= 128) && (tid < 128 + IN_DIM);  // wave 2 stages x
  if (tid < H_SLICE) hshm[slot * H_SLICE + tid] = 0.0f;  // h(0) own slice

  // Dual-probe registers: loop-carried (live across the t-loop) so their
  // physical regs stay reserved under pending dangling writebacks. Parity
  // rule makes stale dangler data un-validatable at the next step.
  uint32x4 rA = {0, 0, 0, 0}, rB = {0, 0, 0, 0};

  for (int t = 0; t < T_STEPS; ++t) {
    // ---- gather h(t): STAGGERED ping-pong dual probe, bounded, fallback ---
    if (poller) {
      const unsigned int* p = pub + (t & 1) * H_DIM + tid * 4;
      const unsigned int tg = (unsigned int)t & 0xFFFFu;
      bool done = false;
      asm volatile("global_load_dwordx4 %0, %2, off sc0 sc1"
                   : "+v"(rA), "+v"(rB) : "v"(p) : "memory");
      // THE R13 FIX: offset B by ~L/2 so A/B sample memory at uniform period
      // ~L/2 (phase self-preserves: each reissue is tied to own retirement).
      __builtin_amdgcn_s_sleep(5);
      #pragma unroll 1
      for (int it = 0; it < 2048; ++it) {
        // issue B; wait until only it may remain -> A (and all older
        // ops: danglers, publish store) retired
        asm volatile("global_load_dwordx4 %1, %2, off sc0 sc1\n\t"
                     "s_waitcnt vmcnt(1)"
                     : "+v"(rA), "+v"(rB) : "v"(p) : "memory");
        if (tag_ok(rA, tg)) {            // B left dangling
          stage4(hshm + tid * 4, rA);
          done = true; break;
        }
        // issue A'; wait -> B retired
        asm volatile("global_load_dwordx4 %0, %2, off sc0 sc1\n\t"
                     "s_waitcnt vmcnt(1)"
                     : "+v"(rA), "+v"(rB) : "v"(p) : "memory");
        if (tag_ok(rB, tg)) {            // A' left dangling
          stage4(hshm + tid * 4, rB);
          done = true; break;
        }
      }
      if (!done) {
        // hang-proof fallback: R6-proven blind probe (fresh regs; rA/rB
        // remain live so pending danglers cannot corrupt other values).
        for (;;) {
          uint32x4 r = load_pkt4(p);
          if (tag_ok(r, tg)) { stage4(hshm + tid * 4, r); break; }
        }
      }
    }
    if (xthr) hshm[H_DIM + (tid - 128)] = x[t * IN_DIM + (tid - 128)];
    __syncthreads();  // barrier B: h(t) + x_t staged

    // ---- matvec: thread (w,l) covers row l, k in [w*136, w*136+136) ----
    const float4* hv = (const float4*)(hshm + w * CHUNK);  // 544B-aligned
    float a0 = 0.f, a1 = 0.f, a2 = 0.f, a3 = 0.f;
    #pragma unroll
    for (int q = 0; q < CHUNK / 4; ++q) {
      const float4 h4 = hv[q];  // wave-uniform broadcast read
      a0 = fmaf(wreg[4 * q + 0], h4.x, a0);
      a1 = fmaf(wreg[4 * q + 1], h4.y, a1);
      a2 = fmaf(wreg[4 * q + 2], h4.z, a2);
      a3 = fmaf(wreg[4 * q + 3], h4.w, a3);
    }
    red[w * 64 + l] = (a0 + a1) + (a2 + a3);
    __syncthreads();  // barrier C: partials ready

    // ---- wave 0: activate (all 64 lanes in parallel), update, publish ----
    if (w == 0) {
      const float g = bias + red[l] + red[64 + l] + red[128 + l] + red[192 + l];
      // lanes 0-15: i (sig), 16-31: f (sig), 32-47: g (tanh), 48-63: o (sig)
      const float act = (l < 32 || l >= 48) ? fast_sigmoid(g) : fast_tanh(g);
      const int j = l & 15;
      const float ig = __shfl(act, j, 64);
      const float fg = __shfl(act, j + 16, 64);
      const float gt = __shfl(act, j + 32, 64);
      const float og = __shfl(act, j + 48, 64);
      if (l < H_SLICE) {
        c = fg * c + ig * gt;
        const float h = og * fast_tanh(c);
        hshm[slot * H_SLICE + l] = h;  // own-slice shortcut (fp32)
        const unsigned int pkt =
            (((unsigned int)(t + 1) & 0xFFFFu) << 16) |
            (unsigned int)__half_as_ushort(__float2half_rn(h));
        store_pkt(pub + ((t + 1) & 1) * H_DIM + slot * H_SLICE + l, pkt);
      }
    }
    // hshm/red hazards covered by barriers B/C (disjoint index sets).
  }

  // retire dangling probes before their registers can be reused
  asm volatile("s_waitcnt vmcnt(0)" : "+v"(rA), "+v"(rB) :: "memory");

  // ---- slot 0: final projection out = h(T) . Wlin + blin ----
  if (slot == 0) {
    if (poller) {  // gather h(T) (parity T&1 == 0); own slice already fp32
      const unsigned int* p = pub + (T_STEPS & 1) * H_DIM + tid * 4;
      const unsigned int tg = (unsigned int)T_STEPS & 0xFFFFu;
      for (;;) {
        uint32x4 r = load_pkt4(p);
        if (tag_ok(r, tg)) { stage4(hshm + tid * 4, r); break; }
      }
    }
    __syncthreads();
    red[tid] = hshm[2 * tid] * Wlin[2 * tid] +
               hshm[2 * tid + 1] * Wlin[2 * tid + 1];
    __syncthreads();
    if (w == 0) {
      float s = red[l] + red[64 + l] + red[128 + l] + red[192 + l];
      #pragma unroll
      for (int off = 32; off > 0; off >>= 1) s += __shfl_down(s, off, 64);
      if (l == 0) out[0] = s + blin[0];
    }
  }
}

extern "C" void kernel_launch(void* const* d_in, const int* in_sizes, int n_in,
                              void* d_out, int out_size, void* d_ws, size_t ws_size,
                              hipStream_t stream) {
  const float* x    = (const float*)d_in[0];
  const float* Wih  = (const float*)d_in[1];
  const float* Whh  = (const float*)d_in[2];
  const float* bih  = (const float*)d_in[3];
  const float* bhh  = (const float*)d_in[4];
  const float* Wlin = (const float*)d_in[5];
  const float* blin = (const float*)d_in[6];
  float* out = (float*)d_out;

  unsigned int* pub = (unsigned int*)d_ws;  // [2][512] u32 = 4096 B

  // d_ws re-poisoned 0xAA before every timed call; zeroed pub encodes
  // (tag=0, h=0) = the initial hidden state.
  hipMemsetAsync(d_ws, 0, 4096, stream);
  hipLaunchKernelGGL(lstm_scan_kernel, dim3(SLOTS), dim3(256), 0, stream,
                     x, Wih, Whh, bih, bhh, Wlin, blin, out, pub);
}

// Round 8
// 29717.444 us; speedup vs baseline: 1.0099x; 1.0099x over previous
//
#include <hip/hip_runtime.h>
#include <hip/hip_fp16.h>
#include <math.h>

// LSTM_11089605558768: T=16384 sequential steps, H=512, IN=32, OUT=1.
// Persistent scan, 32 worker wgs x 256 threads; each wg owns 16 h-elements
// (64 gate rows x 544 k, [W_hh | W_ih] folded).
//
// R14 = R6 (proven 28.6ms) with the publisher moved OFF the polling waves.
// History: R12/R13 falsified the sampling-quantization theory (dual probes
// at period L/2, with and without stagger: 29.9/30.0ms, FETCH +20%, zero
// gain). R14 reverts to R6's single blind probe and fixes a different,
// counter-backed serialization: in R6 the publisher (wave 0, lanes 0-15)
// is ALSO a poller; vmcnt is per-wave, so wave 0's first probe's
// s_waitcnt vmcnt(0) drains its own sc0 sc1 publish store (~LLC round
// trip) before the first tag check. Wave 0's staging is therefore the
// systematic straggler each step, and barrier B inherits it. Fix:
//  - epilogue/publish moved to wave 3 (pure matvec wave, never polls);
//    its store ack drains at the compiler's pre-barrier vmcnt(0), in
//    parallel with waves 0-1's polling (~600cy hidden under ~3000cy poll).
//  - x_t staged by wave 2 (proven in R12/R13 shell): pollers' vmcnt
//    streams are pure probe loads.
//  - Everything else BYTE-IDENTICAL to R6 (R7-R10: any loop-body reshape
//    makes hipcc demote wreg[] to scratch: VGPR 96/88/64/52, WRITE 2x,
//    +800cy/step. Tripwires: VGPR<136, WRITE~65536).

#define T_STEPS 16384
#define IN_DIM  32
#define H_DIM   512
#define SLOTS   32
#define H_SLICE 16      // H_DIM / SLOTS
#define KTOT    544     // H_DIM + IN_DIM
#define CHUNK   136     // KTOT / 4 waves

typedef unsigned int uint32x4 __attribute__((ext_vector_type(4)));

__device__ __forceinline__ float fast_sigmoid(float v) {
  return 1.0f / (1.0f + __expf(-v));
}
__device__ __forceinline__ float fast_tanh(float v) {
  return 2.0f / (1.0f + __expf(-2.0f * v)) - 1.0f;  // 2*sigmoid(2x)-1
}

// --- packet I/O (always LLC-coherent: sc0 sc1) -----------------------------
__device__ __forceinline__ void store_pkt(unsigned int* p, unsigned int v) {
  asm volatile("global_store_dword %0, %1, off sc0 sc1"
               :: "v"(p), "v"(v) : "memory");
}
__device__ __forceinline__ uint32x4 load_pkt4(const unsigned int* p) {
  uint32x4 r;
  asm volatile("global_load_dwordx4 %0, %1, off sc0 sc1\n\ts_waitcnt vmcnt(0)"
               : "=&v"(r) : "v"(p) : "memory");
  return r;
}
__device__ __forceinline__ float pkt_to_f(unsigned int v) {
  return __half2float(__ushort_as_half((unsigned short)(v & 0xFFFFu)));
}
__device__ __forceinline__ bool tag_ok(const uint32x4& r, unsigned int tg) {
  return (r.x >> 16) == tg && (r.y >> 16) == tg &&
         (r.z >> 16) == tg && (r.w >> 16) == tg;
}
__device__ __forceinline__ void stage4(float* dst, const uint32x4& r) {
  float4 hv4;
  hv4.x = pkt_to_f(r.x);
  hv4.y = pkt_to_f(r.y);
  hv4.z = pkt_to_f(r.z);
  hv4.w = pkt_to_f(r.w);
  *(float4*)dst = hv4;  // contiguous float4: 0 bank conflicts (R6-proven)
}

__launch_bounds__(256, 1)
__global__ void lstm_scan_kernel(
    const float* __restrict__ x,     // [T, 32]
    const float* __restrict__ Wih,   // [2048, 32]
    const float* __restrict__ Whh,   // [2048, 512]
    const float* __restrict__ bih,   // [2048]
    const float* __restrict__ bhh,   // [2048]
    const float* __restrict__ Wlin,  // [512]
    const float* __restrict__ blin,  // [1]
    float* __restrict__ out,         // [1]
    unsigned int* pub)               // [2][512] 4B packets (d_ws)
{
  const int slot = blockIdx.x;       // 0..31
  const int tid  = threadIdx.x;
  const int w    = tid >> 6;   // wave 0..3 -> k-chunk
  const int l    = tid & 63;   // lane -> local gate row

  __shared__ __align__(16) float hshm[KTOT];  // [0,512)=h(t), [512,544)=x_t
  __shared__ float red[256];                  // per-wave partials

  // local row l: 0..15 = i, 16..31 = f, 32..47 = g, 48..63 = o
  const int R = (l >> 4) * H_DIM + slot * H_SLICE + (l & 15);

  // Persistent weight slice -> registers, then PIN with opaque asm identity
  // so the compiler cannot rematerialize the loads inside the t-loop.
  float wreg[CHUNK];
  #pragma unroll
  for (int j = 0; j < CHUNK; ++j) {
    const int k = w * CHUNK + j;
    wreg[j] = (k < H_DIM) ? Whh[R * H_DIM + k]
                          : Wih[R * IN_DIM + (k - H_DIM)];
  }
  #pragma unroll
  for (int j = 0; j < CHUNK; ++j)
    asm volatile("v_mov_b32 %0, %0" : "+v"(wreg[j]));

  // Epilogue owner is wave 3 (non-polling): its publish-store ack drains at
  // the pre-barrier vmcnt(0), hidden under waves 0-1's polling.
  const float bias = (w == 3) ? (bih[R] + bhh[R]) : 0.0f;

  float c = 0.0f;  // cell state: wave 3, lanes 0..15 (h index slot*16 + l)

  // Polling assignment (R6-proven): tid<128 polls packets [4*tid, 4*tid+4);
  // own-slot group skipped (wave-3 epilogue provides it in fp32).
  const bool poller = (tid < 128) && ((tid >> 2) != slot);
  const bool xthr   = (tid >= 128) && (tid < 128 + IN_DIM);  // wave 2 stages x
  if (tid < H_SLICE) hshm[slot * H_SLICE + tid] = 0.0f;  // h(0) own slice

  for (int t = 0; t < T_STEPS; ++t) {
    // ---- gather h(t): blind poll, 4 self-validating packets per thread ----
    // Pollers' vmcnt streams contain ONLY probe loads (publisher is wave 3,
    // x-stager is wave 2): first tag check is never gated by a store ack.
    if (poller) {
      const unsigned int* p = pub + (t & 1) * H_DIM + tid * 4;
      const unsigned int tg = (unsigned int)t & 0xFFFFu;
      for (;;) {
        uint32x4 r = load_pkt4(p);
        if (tag_ok(r, tg)) { stage4(hshm + tid * 4, r); break; }
      }
    }
    if (xthr) hshm[H_DIM + (tid - 128)] = x[t * IN_DIM + (tid - 128)];
    __syncthreads();  // barrier B: h(t) + x_t staged

    // ---- matvec: thread (w,l) covers row l, k in [w*136, w*136+136) ----
    const float4* hv = (const float4*)(hshm + w * CHUNK);  // 544B-aligned
    float a0 = 0.f, a1 = 0.f, a2 = 0.f, a3 = 0.f;
    #pragma unroll
    for (int q = 0; q < CHUNK / 4; ++q) {
      const float4 h4 = hv[q];  // wave-uniform broadcast read
      a0 = fmaf(wreg[4 * q + 0], h4.x, a0);
      a1 = fmaf(wreg[4 * q + 1], h4.y, a1);
      a2 = fmaf(wreg[4 * q + 2], h4.z, a2);
      a3 = fmaf(wreg[4 * q + 3], h4.w, a3);
    }
    red[w * 64 + l] = (a0 + a1) + (a2 + a3);
    __syncthreads();  // barrier C: partials ready

    // ---- wave 3: activate (all 64 lanes in parallel), update, publish ----
    if (w == 3) {
      const float g = bias + red[l] + red[64 + l] + red[128 + l] + red[192 + l];
      // lanes 0-15: i (sig), 16-31: f (sig), 32-47: g (tanh), 48-63: o (sig)
      const float act = (l < 32 || l >= 48) ? fast_sigmoid(g) : fast_tanh(g);
      const int j = l & 15;
      const float ig = __shfl(act, j, 64);
      const float fg = __shfl(act, j + 16, 64);
      const float gt = __shfl(act, j + 32, 64);
      const float og = __shfl(act, j + 48, 64);
      if (l < H_SLICE) {
        c = fg * c + ig * gt;
        const float h = og * fast_tanh(c);
        hshm[slot * H_SLICE + l] = h;  // own-slice shortcut (fp32)
        const unsigned int pkt =
            (((unsigned int)(t + 1) & 0xFFFFu) << 16) |
            (unsigned int)__half_as_ushort(__float2half_rn(h));
        store_pkt(pub + ((t + 1) & 1) * H_DIM + slot * H_SLICE + l, pkt);
      }
    }
    // hshm/red hazards covered by barriers B/C (disjoint index sets).
  }

  // ---- slot 0: final projection out = h(T) . Wlin + blin ----
  if (slot == 0) {
    if (poller) {  // gather h(T) (parity T&1 == 0); own slice already fp32
      const unsigned int* p = pub + (T_STEPS & 1) * H_DIM + tid * 4;
      const unsigned int tg = (unsigned int)T_STEPS & 0xFFFFu;
      for (;;) {
        uint32x4 r = load_pkt4(p);
        if (tag_ok(r, tg)) { stage4(hshm + tid * 4, r); break; }
      }
    }
    __syncthreads();
    red[tid] = hshm[2 * tid] * Wlin[2 * tid] +
               hshm[2 * tid + 1] * Wlin[2 * tid + 1];
    __syncthreads();
    if (w == 0) {
      float s = red[l] + red[64 + l] + red[128 + l] + red[192 + l];
      #pragma unroll
      for (int off = 32; off > 0; off >>= 1) s += __shfl_down(s, off, 64);
      if (l == 0) out[0] = s + blin[0];
    }
  }
}

extern "C" void kernel_launch(void* const* d_in, const int* in_sizes, int n_in,
                              void* d_out, int out_size, void* d_ws, size_t ws_size,
                              hipStream_t stream) {
  const float* x    = (const float*)d_in[0];
  const float* Wih  = (const float*)d_in[1];
  const float* Whh  = (const float*)d_in[2];
  const float* bih  = (const float*)d_in[3];
  const float* bhh  = (const float*)d_in[4];
  const float* Wlin = (const float*)d_in[5];
  const float* blin = (const float*)d_in[6];
  float* out = (float*)d_out;

  unsigned int* pub = (unsigned int*)d_ws;  // [2][512] u32 = 4096 B

  // d_ws re-poisoned 0xAA before every timed call; zeroed pub encodes
  // (tag=0, h=0) = the initial hidden state.
  hipMemsetAsync(d_ws, 0, 4096, stream);
  hipLaunchKernelGGL(lstm_scan_kernel, dim3(SLOTS), dim3(256), 0, stream,
                     x, Wih, Whh, bih, bhh, Wlin, blin, out, pub);
}

// Round 10
// 28726.724 us; speedup vs baseline: 1.0447x; 1.0345x over previous
//
#include <hip/hip_runtime.h>
#include <hip/hip_fp16.h>
#include <math.h>

// LSTM_11089605558768: T=16384 sequential steps, H=512, IN=32, OUT=1.
// Persistent scan, 32 worker wgs x 256 threads; each wg owns 16 h-elements
// (64 gate rows x 544 k, [W_hh | W_ih] folded).
//
// R16 = R15 resubmitted byte-identical (R15's bench died in infra:
// "MI355X container failed twice", no counters; hang-audit clean: no
// divergent barriers, same cross-block dependency chain as proven R6/R12/
// R14, all LDS handoffs lgkmcnt-drained, disjoint staging index sets).
//
// Theory under test (from R14 post-mortem): __syncthreads() = FULL
// vmcnt(0)+lgkmcnt(0) drain before s_barrier (documented hipcc behavior).
// R14's publisher-on-wave-3 just moved the publish-ack stall from wave 0's
// first probe to wave 3's barrier entry; R14's wave-2 x-staging EXPOSED the
// x HBM miss (~900cy) that R6 hid under the poll. R15/R16 removes the
// drains instead of relocating them:
//  1. Hot-loop barriers are lgkmcnt-only (raw s_barrier): barriers B/C only
//     guard LDS visibility; vector-memory ops stay in flight across them
//     (AITER/HK pattern: never vmcnt(0) in the main loop).
//  2. Publisher = wave 3 (non-poller): publish ack drains NOWHERE in the
//     loop - fire-and-forget, retires under the next step's poll.
//  3. x staged by wave 2 WITH register prefetch: x(t+1) issued at step t,
//     consumed at t+1 (compiler's minimal vmcnt wait, satisfied ~1700cy
//     later). Streaming-HBM miss off the critical path.
//  Pollers' vmcnt streams are pure probe loads. Matvec/poll/epilogue code
//  otherwise BYTE-IDENTICAL to R6 (R7-R10: reshapes break the wreg pin:
//  VGPR<136, WRITE 2x, +800cy/step. Tripwires: VGPR<136, WRITE~65536).

#define T_STEPS 16384
#define IN_DIM  32
#define H_DIM   512
#define SLOTS   32
#define H_SLICE 16      // H_DIM / SLOTS
#define KTOT    544     // H_DIM + IN_DIM
#define CHUNK   136     // KTOT / 4 waves

typedef unsigned int uint32x4 __attribute__((ext_vector_type(4)));

// LDS-only barrier: drain ds ops, sync, compiler fence. No vmcnt drain.
#define BAR_LDS() do {                                      \
    asm volatile("s_waitcnt lgkmcnt(0)" ::: "memory");      \
    __builtin_amdgcn_s_barrier();                           \
    asm volatile("" ::: "memory");                          \
  } while (0)

__device__ __forceinline__ float fast_sigmoid(float v) {
  return 1.0f / (1.0f + __expf(-v));
}
__device__ __forceinline__ float fast_tanh(float v) {
  return 2.0f / (1.0f + __expf(-2.0f * v)) - 1.0f;  // 2*sigmoid(2x)-1
}

// --- packet I/O (always LLC-coherent: sc0 sc1) -----------------------------
__device__ __forceinline__ void store_pkt(unsigned int* p, unsigned int v) {
  asm volatile("global_store_dword %0, %1, off sc0 sc1"
               :: "v"(p), "v"(v) : "memory");
}
__device__ __forceinline__ uint32x4 load_pkt4(const unsigned int* p) {
  uint32x4 r;
  asm volatile("global_load_dwordx4 %0, %1, off sc0 sc1\n\ts_waitcnt vmcnt(0)"
               : "=&v"(r) : "v"(p) : "memory");
  return r;
}
__device__ __forceinline__ float pkt_to_f(unsigned int v) {
  return __half2float(__ushort_as_half((unsigned short)(v & 0xFFFFu)));
}
__device__ __forceinline__ bool tag_ok(const uint32x4& r, unsigned int tg) {
  return (r.x >> 16) == tg && (r.y >> 16) == tg &&
         (r.z >> 16) == tg && (r.w >> 16) == tg;
}
__device__ __forceinline__ void stage4(float* dst, const uint32x4& r) {
  float4 hv4;
  hv4.x = pkt_to_f(r.x);
  hv4.y = pkt_to_f(r.y);
  hv4.z = pkt_to_f(r.z);
  hv4.w = pkt_to_f(r.w);
  *(float4*)dst = hv4;  // contiguous float4: 0 bank conflicts (R6-proven)
}

__launch_bounds__(256, 1)
__global__ void lstm_scan_kernel(
    const float* __restrict__ x,     // [T, 32]
    const float* __restrict__ Wih,   // [2048, 32]
    const float* __restrict__ Whh,   // [2048, 512]
    const float* __restrict__ bih,   // [2048]
    const float* __restrict__ bhh,   // [2048]
    const float* __restrict__ Wlin,  // [512]
    const float* __restrict__ blin,  // [1]
    float* __restrict__ out,         // [1]
    unsigned int* pub)               // [2][512] 4B packets (d_ws)
{
  const int slot = blockIdx.x;       // 0..31
  const int tid  = threadIdx.x;
  const int w    = tid >> 6;   // wave 0..3 -> k-chunk
  const int l    = tid & 63;   // lane -> local gate row

  __shared__ __align__(16) float hshm[KTOT];  // [0,512)=h(t), [512,544)=x_t
  __shared__ float red[256];                  // per-wave partials

  // local row l: 0..15 = i, 16..31 = f, 32..47 = g, 48..63 = o
  const int R = (l >> 4) * H_DIM + slot * H_SLICE + (l & 15);

  // Persistent weight slice -> registers, then PIN with opaque asm identity
  // so the compiler cannot rematerialize the loads inside the t-loop.
  float wreg[CHUNK];
  #pragma unroll
  for (int j = 0; j < CHUNK; ++j) {
    const int k = w * CHUNK + j;
    wreg[j] = (k < H_DIM) ? Whh[R * H_DIM + k]
                          : Wih[R * IN_DIM + (k - H_DIM)];
  }
  #pragma unroll
  for (int j = 0; j < CHUNK; ++j)
    asm volatile("v_mov_b32 %0, %0" : "+v"(wreg[j]));

  // Epilogue owner = wave 3 (non-polling): with lgkmcnt-only barriers its
  // publish-store ack never blocks anything in the loop.
  const float bias = (w == 3) ? (bih[R] + bhh[R]) : 0.0f;

  float c = 0.0f;  // cell state: wave 3, lanes 0..15 (h index slot*16 + l)

  // Polling assignment (R6-proven): tid<128 polls packets [4*tid, 4*tid+4);
  // own-slot group skipped (wave-3 epilogue provides it in fp32).
  const bool poller = (tid < 128) && ((tid >> 2) != slot);
  const bool xthr   = (tid >= 128) && (tid < 128 + IN_DIM);  // wave 2 stages x
  const int  xi     = tid - 128;                             // 0..31 for xthr
  if (tid < H_SLICE) hshm[slot * H_SLICE + tid] = 0.0f;  // h(0) own slice

  // x register prefetch (wave 2): x(0) issued pre-loop; x(t+1) issued at
  // step t, consumed (LDS write) at t+1. Never gates a barrier.
  float xcur = xthr ? x[xi] : 0.0f;

  for (int t = 0; t < T_STEPS; ++t) {
    // ---- gather h(t): blind poll, 4 self-validating packets per thread ----
    // Poller vmcnt streams contain ONLY probe loads.
    if (poller) {
      const unsigned int* p = pub + (t & 1) * H_DIM + tid * 4;
      const unsigned int tg = (unsigned int)t & 0xFFFFu;
      for (;;) {
        uint32x4 r = load_pkt4(p);
        if (tag_ok(r, tg)) { stage4(hshm + tid * 4, r); break; }
      }
    }
    if (xthr) {
      hshm[H_DIM + xi] = xcur;  // x(t) from prefetch (no load on this path)
      const int tn = (t + 1 < T_STEPS) ? t + 1 : t;
      xcur = x[tn * IN_DIM + xi];  // prefetch x(t+1); in flight across barriers
    }
    BAR_LDS();  // barrier B: h(t) + x_t staged (LDS-only drain)

    // ---- matvec: thread (w,l) covers row l, k in [w*136, w*136+136) ----
    const float4* hv = (const float4*)(hshm + w * CHUNK);  // 544B-aligned
    float a0 = 0.f, a1 = 0.f, a2 = 0.f, a3 = 0.f;
    #pragma unroll
    for (int q = 0; q < CHUNK / 4; ++q) {
      const float4 h4 = hv[q];  // wave-uniform broadcast read
      a0 = fmaf(wreg[4 * q + 0], h4.x, a0);
      a1 = fmaf(wreg[4 * q + 1], h4.y, a1);
      a2 = fmaf(wreg[4 * q + 2], h4.z, a2);
      a3 = fmaf(wreg[4 * q + 3], h4.w, a3);
    }
    red[w * 64 + l] = (a0 + a1) + (a2 + a3);
    BAR_LDS();  // barrier C: partials ready (LDS-only drain)

    // ---- wave 3: activate (all 64 lanes in parallel), update, publish ----
    if (w == 3) {
      const float g = bias + red[l] + red[64 + l] + red[128 + l] + red[192 + l];
      // lanes 0-15: i (sig), 16-31: f (sig), 32-47: g (tanh), 48-63: o (sig)
      const float act = (l < 32 || l >= 48) ? fast_sigmoid(g) : fast_tanh(g);
      const int j = l & 15;
      const float ig = __shfl(act, j, 64);
      const float fg = __shfl(act, j + 16, 64);
      const float gt = __shfl(act, j + 32, 64);
      const float og = __shfl(act, j + 48, 64);
      if (l < H_SLICE) {
        c = fg * c + ig * gt;
        const float h = og * fast_tanh(c);
        hshm[slot * H_SLICE + l] = h;  // own-slice shortcut (fp32)
        const unsigned int pkt =
            (((unsigned int)(t + 1) & 0xFFFFu) << 16) |
            (unsigned int)__half_as_ushort(__float2half_rn(h));
        store_pkt(pub + ((t + 1) & 1) * H_DIM + slot * H_SLICE + l, pkt);
        // ack drains nowhere in the loop: fire-and-forget.
      }
    }
    // hshm/red hazards covered by barriers B/C (disjoint index sets).
  }

  // drain any in-flight ops (publish stores, x prefetch) before cold path
  asm volatile("s_waitcnt vmcnt(0)" ::: "memory");

  // ---- slot 0: final projection out = h(T) . Wlin + blin ----
  if (slot == 0) {
    if (poller) {  // gather h(T) (parity T&1 == 0); own slice already fp32
      const unsigned int* p = pub + (T_STEPS & 1) * H_DIM + tid * 4;
      const unsigned int tg = (unsigned int)T_STEPS & 0xFFFFu;
      for (;;) {
        uint32x4 r = load_pkt4(p);
        if (tag_ok(r, tg)) { stage4(hshm + tid * 4, r); break; }
      }
    }
    __syncthreads();
    red[tid] = hshm[2 * tid] * Wlin[2 * tid] +
               hshm[2 * tid + 1] * Wlin[2 * tid + 1];
    __syncthreads();
    if (w == 0) {
      float s = red[l] + red[64 + l] + red[128 + l] + red[192 + l];
      #pragma unroll
      for (int off = 32; off > 0; off >>= 1) s += __shfl_down(s, off, 64);
      if (l == 0) out[0] = s + blin[0];
    }
  }
}

extern "C" void kernel_launch(void* const* d_in, const int* in_sizes, int n_in,
                              void* d_out, int out_size, void* d_ws, size_t ws_size,
                              hipStream_t stream) {
  const float* x    = (const float*)d_in[0];
  const float* Wih  = (const float*)d_in[1];
  const float* Whh  = (const float*)d_in[2];
  const float* bih  = (const float*)d_in[3];
  const float* bhh  = (const float*)d_in[4];
  const float* Wlin = (const float*)d_in[5];
  const float* blin = (const float*)d_in[6];
  float* out = (float*)d_out;

  unsigned int* pub = (unsigned int*)d_ws;  // [2][512] u32 = 4096 B

  // d_ws re-poisoned 0xAA before every timed call; zeroed pub encodes
  // (tag=0, h=0) = the initial hidden state.
  hipMemsetAsync(d_ws, 0, 4096, stream);
  hipLaunchKernelGGL(lstm_scan_kernel, dim3(SLOTS), dim3(256), 0, stream,
                     x, Wih, Whh, bih, bhh, Wlin, blin, out, pub);
}